// Round 15
// baseline (2851.456 us; speedup 1.0000x reference)
//
#include <hip/hip_runtime.h>
#include <hip/hip_bf16.h>

typedef __attribute__((ext_vector_type(8))) short bf16x8;
typedef __attribute__((ext_vector_type(4))) short bf16x4;
typedef __attribute__((ext_vector_type(4))) float f32x4;

#define DEVI static __device__ __forceinline__

DEVI unsigned short f2bf(float f) {
  __hip_bfloat16 h = __float2bfloat16(f);
  return __builtin_bit_cast(unsigned short, h);
}

DEVI f32x4 mfma16(bf16x8 a, bf16x8 b, f32x4 c) {
  return __builtin_amdgcn_mfma_f32_16x16x32_bf16(a, b, c, 0, 0, 0);
}

// async global->LDS, 16B per lane; LDS dest is wave-uniform base + lane*16
DEVI void gload16(const unsigned short* g, unsigned short* l) {
  __builtin_amdgcn_global_load_lds(
      (const __attribute__((address_space(1))) void*)g,
      (__attribute__((address_space(3))) void*)l, 16, 0, 0);
}

// fast erf (Abramowitz-Stegun 7.1.26, |err| <= 1.5e-7)
DEVI float erf_fast(float x) {
  float ax = fabsf(x);
  float t = 1.f / (1.f + 0.3275911f * ax);
  float poly = ((((1.061405429f * t - 1.453152027f) * t + 1.421413741f) * t -
                 0.284496736f) * t + 0.254829592f) * t;
  float e = __expf(-x * x);
  float er = 1.f - poly * e;
  return copysignf(er, x);
}

// ---------------- im2col: x[32,3,224,224] -> A[6272][768] bf16 -------------
__global__ __launch_bounds__(256) void k_im2col(const float* __restrict__ x,
                                                unsigned short* __restrict__ A) {
  int t = blockIdx.x * 256 + threadIdx.x;
  int m = t / 192;
  int qq = t - m * 192;
  int kk = qq * 4;
  int c = kk >> 8;
  int r = kk & 255;
  int i = r >> 4;
  int j = r & 15;
  int b = m / 196;
  int s = m - b * 196;
  int ph = s / 14;
  int pw = s - ph * 14;
  const float* src = x + ((size_t)((b * 3 + c) * 224 + ph * 16 + i)) * 224 + pw * 16 + j;
  f32x4 v = *reinterpret_cast<const f32x4*>(src);
  bf16x4 o;
  o[0] = (short)f2bf(v[0]); o[1] = (short)f2bf(v[1]);
  o[2] = (short)f2bf(v[2]); o[3] = (short)f2bf(v[3]);
  *reinterpret_cast<bf16x4*>(A + (size_t)m * 768 + kk) = o;
}

// ---------------- elementwise f32 -> bf16 (conv_w is already [N][K]) -------
__global__ __launch_bounds__(256) void k_cvt(const float* __restrict__ in,
                                             unsigned short* __restrict__ out) {
  int t = blockIdx.x * 256 + threadIdx.x;
  f32x4 v = *reinterpret_cast<const f32x4*>(in + (size_t)t * 4);
  bf16x4 o;
  o[0] = (short)f2bf(v[0]); o[1] = (short)f2bf(v[1]);
  o[2] = (short)f2bf(v[2]); o[3] = (short)f2bf(v[3]);
  *reinterpret_cast<bf16x4*>(out + (size_t)t * 4) = o;
}

// ---------------- transpose-convert: W[K][N] f32 -> Wt[N][K] bf16 ----------
// LDS layout: tile[row][ (g ^ (row&15))*4 + (col&3) ], g = col>>2.
// Stride 66 shorts (33 dwords, ==1 mod 32) + group-XOR -> both LDS phases
// ~2-way bank aliasing (free).  Element (row,col) recoverable bijectively.
DEVI void transpose_tile(const float* __restrict__ in, unsigned short* __restrict__ out,
                         int K, int N, int kt, int nt, unsigned short (*tile)[66]) {
  int r = threadIdx.x >> 4;
  int c4 = (threadIdx.x & 15) * 4;
  int k0 = kt * 64, n0 = nt * 64;
#pragma unroll
  for (int rr0 = 0; rr0 < 4; rr0++) {
    int rr = r + rr0 * 16;
    f32x4 v = *reinterpret_cast<const f32x4*>(in + (size_t)(k0 + rr) * N + n0 + c4);
    unsigned int lo = (unsigned int)f2bf(v[0]) | ((unsigned int)f2bf(v[1]) << 16);
    unsigned int hi = (unsigned int)f2bf(v[2]) | ((unsigned int)f2bf(v[3]) << 16);
    int g = ((c4 >> 2) ^ (rr & 15)) * 4;
    unsigned int* dst = reinterpret_cast<unsigned int*>(&tile[rr][g]);
    dst[0] = lo;
    dst[1] = hi;
  }
  __syncthreads();
#pragma unroll
  for (int rr0 = 0; rr0 < 4; rr0++) {
    int rr = r + rr0 * 16;  // output row (n-index); gathers source rows c4..c4+3
    bf16x4 o;
#pragma unroll
    for (int x = 0; x < 4; x++) {
      int row = c4 + x;
      int gs = ((rr >> 2) ^ (row & 15)) * 4 + (rr & 3);
      o[x] = (short)tile[row][gs];
    }
    *reinterpret_cast<bf16x4*>(out + (size_t)(n0 + rr) * K + k0 + c4) = o;
  }
}

DEVI void wconvert_body(const float* wq, const float* wk, const float* wv,
                        const float* w1, const float* w2,
                        unsigned short* wqkvT, unsigned short* w1T,
                        unsigned short* w2T, int bid,
                        unsigned short (*tile)[66]) {
  if (bid < 432) {
    int mm = bid / 144, t2 = bid - mm * 144;
    const float* in = (mm == 0) ? wq : ((mm == 1) ? wk : wv);
    transpose_tile(in, wqkvT + (size_t)mm * 768 * 768, 768, 768, t2 / 12, t2 % 12, tile);
  } else if (bid < 1008) {
    int t2 = bid - 432;
    transpose_tile(w1, w1T, 768, 3072, t2 / 48, t2 % 48, tile);
  } else {
    int t2 = bid - 1008;
    transpose_tile(w2, w2T, 3072, 768, t2 / 12, t2 % 12, tile);
  }
}

__global__ __launch_bounds__(256) void k_wconvert(
    const float* __restrict__ wq, const float* __restrict__ wk, const float* __restrict__ wv,
    const float* __restrict__ w1, const float* __restrict__ w2,
    unsigned short* __restrict__ wqkvT, unsigned short* __restrict__ w1T,
    unsigned short* __restrict__ w2T) {
  __shared__ unsigned short tile[64][66];
  wconvert_body(wq, wk, wv, w1, w2, wqkvT, w1T, w2T, blockIdx.x, tile);
}

// all-12-layer variant (one launch; used when workspace permits)
__global__ __launch_bounds__(256) void k_wconvert_all(
    const float* __restrict__ wq, const float* __restrict__ wk, const float* __restrict__ wv,
    const float* __restrict__ w1, const float* __restrict__ w2,
    unsigned short* __restrict__ wqkvT, unsigned short* __restrict__ w1T,
    unsigned short* __restrict__ w2T) {
  __shared__ unsigned short tile[64][66];
  int l = blockIdx.x / 1584, bid = blockIdx.x - l * 1584;
  wconvert_body(wq + (size_t)l * 589824, wk + (size_t)l * 589824, wv + (size_t)l * 589824,
                w1 + (size_t)l * 2359296, w2 + (size_t)l * 2359296,
                wqkvT + (size_t)l * 1769472, w1T + (size_t)l * 2359296,
                w2T + (size_t)l * 2359296, bid, tile);
}

// -------- LayerNorm (optionally fused with split-K combine) ----------------
// RED=0: xn = LN(h)
// RED=1: v = h + part; h = v; xn = LN(v)
template <int RED>
__global__ __launch_bounds__(256) void k_ln(float* __restrict__ h,
                                            const float* __restrict__ part,
                                            const float* __restrict__ sc,
                                            const float* __restrict__ bi,
                                            unsigned short* __restrict__ xn) {
  int wave = threadIdx.x >> 6, lane = threadIdx.x & 63;
  int row = blockIdx.x * 4 + wave;
  float* hr = h + (size_t)row * 768;
  const float* pr = part + (size_t)row * 768;
  f32x4 v[3];
  float sum = 0.f;
#pragma unroll
  for (int i = 0; i < 3; i++) {
    v[i] = *reinterpret_cast<const f32x4*>(hr + i * 256 + lane * 4);
    if (RED) {
      f32x4 pv = *reinterpret_cast<const f32x4*>(pr + i * 256 + lane * 4);
#pragma unroll
      for (int c = 0; c < 4; c++) v[i][c] += pv[c];
      *reinterpret_cast<f32x4*>(hr + i * 256 + lane * 4) = v[i];
    }
    sum += v[i][0] + v[i][1] + v[i][2] + v[i][3];
  }
#pragma unroll
  for (int m = 1; m < 64; m <<= 1) sum += __shfl_xor(sum, m, 64);
  float mean = sum * (1.f / 768.f);
  float var = 0.f;
#pragma unroll
  for (int i = 0; i < 3; i++)
#pragma unroll
    for (int c = 0; c < 4; c++) { float d = v[i][c] - mean; var += d * d; }
#pragma unroll
  for (int m = 1; m < 64; m <<= 1) var += __shfl_xor(var, m, 64);
  float rs = rsqrtf(var * (1.f / 768.f) + 1e-5f);
#pragma unroll
  for (int i = 0; i < 3; i++) {
    int col = i * 256 + lane * 4;
    f32x4 s4 = *reinterpret_cast<const f32x4*>(sc + col);
    f32x4 b4 = *reinterpret_cast<const f32x4*>(bi + col);
    bf16x4 o;
#pragma unroll
    for (int c = 0; c < 4; c++) o[c] = (short)f2bf((v[i][c] - mean) * rs * s4[c] + b4[c]);
    *reinterpret_cast<bf16x4*>(xn + (size_t)row * 768 + col) = o;
  }
}

// ---------------- 128xBN-tile GEMM (R4-proven structure), split-K ----------
// EPI 0 (BN=128): patch -> h = acc + conv_b[n] + pos[s][n]      (z=1)
// EPI 3 (BN=64):  mlp2  -> split0: h += acc + b2[n]; split1: pOut = acc (z=2)
template <int EPI, int BN>
__global__ __launch_bounds__(256) void k_gemm(
    const unsigned short* __restrict__ A, const unsigned short* __restrict__ Bt, int K,
    int nks, const float* __restrict__ bias, const float* __restrict__ aux,
    float* __restrict__ outF, float* __restrict__ pOut) {
  constexpr int NI = BN / 32;  // B frags per wave
  constexpr int BR = BN / 64;  // B staging rounds
  __shared__ __align__(16) unsigned short As[2][128 * 32];
  __shared__ __align__(16) unsigned short Bs[2][BN * 32];

  int GX = gridDim.x, GY = gridDim.y, GZ = gridDim.z;
  int nb = GX * GY * GZ;
  int lin = (blockIdx.z * GY + blockIdx.y) * GX + blockIdx.x;
  int q = nb >> 3, r8 = nb & 7;
  int xcd = lin & 7, off = lin >> 3;
  int wid = (xcd < r8 ? xcd * (q + 1) : r8 * (q + 1) + (xcd - r8) * q) + off;
  int t2 = GX * GY;
  int sz = wid / t2;
  int w2 = wid - sz * t2;
  const int GM = 8;
  int per = GM * GX;
  int g = w2 / per;
  int first_m = g * GM;
  int gm = min(GM, GY - first_m);
  int rem = w2 - g * per;
  int mt = first_m + rem % gm;
  int nt = rem / gm;
  int m0 = mt * 128, n0 = nt * BN;
  int kb = sz * nks * 32;

  int tid = threadIdx.x;
  int wave = tid >> 6, lane = tid & 63;
  int wm = (wave >> 1) * 64, wn = (wave & 1) * (NI * 16);
  int lr = lane & 15, lg = lane >> 4;

  f32x4 acc[4][NI];
  const f32x4 fz = {0.f, 0.f, 0.f, 0.f};
#pragma unroll
  for (int i = 0; i < 4; i++)
#pragma unroll
    for (int j = 0; j < NI; j++) acc[i][j] = fz;

  int srow = wave * 16 + (lane >> 2);
  int scol = (lane & 3) * 8;
  const unsigned short* Ag = A + (size_t)(m0 + srow) * K + scol + kb;
  const unsigned short* Bg = Bt + (size_t)(n0 + srow) * K + scol + kb;
  int lofs = wave * 16 * 32;

#pragma unroll
  for (int j = 0; j < 2; j++)
    gload16(Ag + (size_t)j * 64 * K, &As[0][lofs + j * 64 * 32]);
#pragma unroll
  for (int j = 0; j < BR; j++)
    gload16(Bg + (size_t)j * 64 * K, &Bs[0][lofs + j * 64 * 32]);
  __syncthreads();

  for (int kt = 0; kt < nks - 1; kt++) {
    int cur = kt & 1;
    int k0 = (kt + 1) << 5;
#pragma unroll
    for (int j = 0; j < 2; j++)
      gload16(Ag + (size_t)j * 64 * K + k0, &As[cur ^ 1][lofs + j * 64 * 32]);
#pragma unroll
    for (int j = 0; j < BR; j++)
      gload16(Bg + (size_t)j * 64 * K + k0, &Bs[cur ^ 1][lofs + j * 64 * 32]);
    bf16x8 a[4], b[NI];
#pragma unroll
    for (int i = 0; i < 4; i++)
      a[i] = *reinterpret_cast<const bf16x8*>(&As[cur][(wm + i * 16 + lr) * 32 + lg * 8]);
#pragma unroll
    for (int i = 0; i < NI; i++)
      b[i] = *reinterpret_cast<const bf16x8*>(&Bs[cur][(wn + i * 16 + lr) * 32 + lg * 8]);
#pragma unroll
    for (int mi = 0; mi < 4; mi++)
#pragma unroll
      for (int ni = 0; ni < NI; ni++) acc[mi][ni] = mfma16(a[mi], b[ni], acc[mi][ni]);
    __syncthreads();
  }
  {
    int cur = (nks - 1) & 1;
    bf16x8 a[4], b[NI];
#pragma unroll
    for (int i = 0; i < 4; i++)
      a[i] = *reinterpret_cast<const bf16x8*>(&As[cur][(wm + i * 16 + lr) * 32 + lg * 8]);
#pragma unroll
    for (int i = 0; i < NI; i++)
      b[i] = *reinterpret_cast<const bf16x8*>(&Bs[cur][(wn + i * 16 + lr) * 32 + lg * 8]);
#pragma unroll
    for (int mi = 0; mi < 4; mi++)
#pragma unroll
      for (int ni = 0; ni < NI; ni++) acc[mi][ni] = mfma16(a[mi], b[ni], acc[mi][ni]);
  }

#pragma unroll
  for (int mi = 0; mi < 4; mi++) {
    int mb = m0 + wm + mi * 16 + lg * 4;
    int bb = mb / 196;
    int s0 = mb - bb * 196;
#pragma unroll
    for (int ni = 0; ni < NI; ni++) {
      int n = n0 + wn + ni * 16 + lr;
      int s = s0;
#pragma unroll
      for (int r = 0; r < 4; r++) {
        int m = mb + r;
        float val = acc[mi][ni][r];
        if (EPI == 0) {
          outF[(size_t)m * 768 + n] = val + bias[n] + aux[(size_t)s * 768 + n];
          s++;
          if (s == 196) s = 0;
        } else {
          if (sz == 0) outF[(size_t)m * 768 + n] += val + bias[n];
          else pOut[(size_t)m * 768 + n] = val;
        }
      }
    }
  }
}

// ---------------- mean over tokens (+ split-K combine) ---------------------
__global__ __launch_bounds__(256) void k_mean_r(const float* __restrict__ h,
                                                const float* __restrict__ part,
                                                float* __restrict__ hm) {
  int b = blockIdx.x, d = blockIdx.y * 256 + threadIdx.x;
  float acc = 0.f;
  for (int s = 0; s < 196; s++) {
    size_t i = (size_t)(b * 196 + s) * 768 + d;
    acc += h[i] + part[i];
  }
  hm[b * 768 + d] = acc * (1.f / 196.f);
}

// ---------------- 256-tile 8-wave GEMM, quad-buffer + 2-phase/K-tile -------
// (R10/R13-proven; unchanged)  EPI 1: qkv scatter bf16; EPI 2: gelu->bf16.
template <int EPI>
__global__ __launch_bounds__(512, 2) void k_gemm256p(
    const unsigned short* __restrict__ A, const unsigned short* __restrict__ Bt,
    const float* __restrict__ bias, unsigned short* __restrict__ outB) {
  const int K = 768, NK = 24;
  __shared__ __align__(16) unsigned short LDS[4][16384];
  const int MVALID = 6272;

  int GX = gridDim.x, GY = gridDim.y;
  int nb = GX * GY;
  int lin = blockIdx.y * GX + blockIdx.x;
  int q = nb >> 3, r8 = nb & 7;
  int xcd = lin & 7, off = lin >> 3;
  int wid = (xcd < r8 ? xcd * (q + 1) : r8 * (q + 1) + (xcd - r8) * q) + off;
  const int GM = 4;
  int per = GM * GX;
  int g = wid / per;
  int first_m = g * GM;
  int gm = min(GM, GY - first_m);
  int rem = wid - g * per;
  int mt = first_m + rem % gm;
  int nt = rem / gm;
  int m0 = mt * 256, n0 = nt * 256;

  int tid = threadIdx.x;
  int w = tid >> 6, lane = tid & 63;
  int wm = w >> 2, wn = w & 3;
  int lr = lane & 15, lg = lane >> 4;

  f32x4 acc[8][4];
  const f32x4 fz = {0.f, 0.f, 0.f, 0.f};
#pragma unroll
  for (int i = 0; i < 8; i++)
#pragma unroll
    for (int j = 0; j < 4; j++) acc[i][j] = fz;

  int srow = w * 16 + (lane >> 2);
  int scol = ((lane & 3) ^ ((lane >> 3) & 3)) * 8;
  const unsigned short* Ag = A + (size_t)(m0 + srow) * K + scol;
  const unsigned short* Bg = Bt + (size_t)(n0 + srow) * K + scol;
  int ldst = w * 512;

  int colsw = (lg ^ ((lr >> 1) & 3)) * 8;
  int rofA = wm * 4096 + lr * 32 + colsw;
  int rofB = 8192 + wn * 2048 + lr * 32 + colsw;

#define STAGEA(kt)                                                          \
  {                                                                         \
    unsigned short* d_ = &LDS[(kt) & 3][0];                                 \
    const unsigned short* a_ = Ag + (kt) * 32;                              \
    gload16(a_, d_ + ldst);                                                 \
    gload16(a_ + (size_t)128 * K, d_ + 4096 + ldst);                        \
  }
#define STAGEB(kt)                                                          \
  {                                                                         \
    unsigned short* d_ = &LDS[(kt) & 3][0];                                 \
    const unsigned short* b_ = Bg + (kt) * 32;                              \
    gload16(b_, d_ + 8192 + ldst);                                          \
    gload16(b_ + (size_t)128 * K, d_ + 12288 + ldst);                       \
  }

#define KTILE(ktv, VMSTR, STG, LAST)                                         \
  {                                                                          \
    const int kt_ = (ktv);                                                   \
    const unsigned short* buf_ = &LDS[kt_ & 3][0];                           \
    bf16x8 afr[8], bfr[2];                                                   \
    _Pragma("unroll") for (int mi = 0; mi < 8; mi++) afr[mi] =               \
        *reinterpret_cast<const bf16x8*>(buf_ + rofA + mi * 512);            \
    _Pragma("unroll") for (int ni = 0; ni < 2; ni++) bfr[ni] =               \
        *reinterpret_cast<const bf16x8*>(buf_ + rofB + ni * 512);            \
    if (STG) STAGEA(kt_ + 3);                                                \
    asm volatile("s_waitcnt lgkmcnt(0)" ::: "memory");                       \
    __builtin_amdgcn_sched_barrier(0);                                       \
    __builtin_amdgcn_s_setprio(1);                                           \
    _Pragma("unroll") for (int mi = 0; mi < 8; mi++)                         \
        _Pragma("unroll") for (int ni = 0; ni < 2; ni++)                     \
            acc[mi][ni] = mfma16(afr[mi], bfr[ni], acc[mi][ni]);             \
    __builtin_amdgcn_s_setprio(0);                                           \
    __builtin_amdgcn_s_barrier();                                            \
    _Pragma("unroll") for (int ni = 0; ni < 2; ni++) bfr[ni] =               \
        *reinterpret_cast<const bf16x8*>(buf_ + rofB + (2 + ni) * 512);      \
    if (STG) STAGEB(kt_ + 3);                                                \
    asm volatile("s_waitcnt lgkmcnt(0)" ::: "memory");                       \
    __builtin_amdgcn_sched_barrier(0);                                       \
    __builtin_amdgcn_s_setprio(1);                                           \
    _Pragma("unroll") for (int mi = 0; mi < 8; mi++)                         \
        _Pragma("unroll") for (int ni = 0; ni < 2; ni++)                     \
            acc[mi][2 + ni] = mfma16(afr[mi], bfr[ni], acc[mi][2 + ni]);     \
    __builtin_amdgcn_s_setprio(0);                                           \
    if (!LAST) {                                                             \
      asm volatile("s_waitcnt vmcnt(" VMSTR ")" ::: "memory");               \
      __builtin_amdgcn_s_barrier();                                          \
    }                                                                        \
  }

  STAGEA(0); STAGEB(0);
  STAGEA(1); STAGEB(1);
  STAGEA(2); STAGEB(2);
  asm volatile("s_waitcnt vmcnt(8)" ::: "memory");
  __builtin_amdgcn_s_barrier();

  for (int kt = 0; kt < NK - 3; kt++) KTILE(kt, "8", true, false);
  KTILE(NK - 3, "4", false, false);
  KTILE(NK - 2, "0", false, false);
  KTILE(NK - 1, "0", false, true);
#undef KTILE
#undef STAGEA
#undef STAGEB

  if (EPI == 1) {
#pragma unroll
    for (int ni = 0; ni < 4; ni++) {
      int n = n0 + wn * 64 + ni * 16 + lr;
      int which = (n >= 1536) ? 2 : ((n >= 768) ? 1 : 0);
      int n7 = n - which * 768;
      int hd = n7 >> 6, dh = n7 & 63;
      unsigned short* ob = outB + (size_t)which * 4816896 + dh;
#pragma unroll
      for (int mi = 0; mi < 8; mi++) {
        int mb = m0 + wm * 128 + mi * 16 + lg * 4;
        if (mb >= MVALID) continue;
        int bb = mb / 196;
        int s = mb - bb * 196;
#pragma unroll
        for (int r = 0; r < 4; r++) {
          ob[((size_t)((bb * 12 + hd) * 196 + s) << 6)] = f2bf(acc[mi][ni][r]);
          s++;
          if (s == 196) { s = 0; bb++; }
        }
      }
    }
  } else {
#pragma unroll
    for (int mi = 0; mi < 8; mi++) {
      int mb = m0 + wm * 128 + mi * 16 + lg * 4;
      if (mb >= MVALID) continue;
#pragma unroll
      for (int ni = 0; ni < 4; ni++) {
        int n = n0 + wn * 64 + ni * 16 + lr;
#pragma unroll
        for (int r = 0; r < 4; r++) {
          int m = mb + r;
          float u = acc[mi][ni][r] + bias[n];
          float gg = 0.5f * u * (1.f + erf_fast(u * 0.70710678118654752f));
          outB[(size_t)m * 3072 + n] = f2bf(gg);
        }
      }
    }
  }
}

// ---------------- attention: 512 threads (8 waves), 2 strips/wave ----------
__global__ __launch_bounds__(512) void k_attn(const unsigned short* __restrict__ q,
                                              const unsigned short* __restrict__ k,
                                              const unsigned short* __restrict__ v,
                                              float* __restrict__ h) {
  __shared__ __align__(16) unsigned short Kl[208][72];
  __shared__ __align__(16) unsigned short Vt[64][248];
  __shared__ __align__(16) unsigned short Sc[8][16][232];
  int bh = blockIdx.x;
  int b = bh / 12, hh = bh - b * 12;
  size_t base = (size_t)bh * 196 * 64;
  int tid = threadIdx.x, wave = tid >> 6, lane = tid & 63;
  int lr = lane & 15, lg = lane >> 4;

  const bf16x8 bz = {0, 0, 0, 0, 0, 0, 0, 0};
  for (int u = tid; u < 208 * 8; u += 512) {
    int row = u >> 3, c8 = (u & 7) * 8;
    bf16x8 val = bz;
    if (row < 196) val = *reinterpret_cast<const bf16x8*>(k + base + row * 64 + c8);
    *reinterpret_cast<bf16x8*>(&Kl[row][c8]) = val;
  }
  for (int u = tid; u < 224 * 8; u += 512) {
    int t = u >> 3, d8 = (u & 7) * 8;
    bf16x8 val = bz;
    if (t < 196) val = *reinterpret_cast<const bf16x8*>(v + base + t * 64 + d8);
#pragma unroll
    for (int i = 0; i < 8; i++) Vt[d8 + i][t] = (unsigned short)val[i];
  }
  for (int i2 = lane; i2 < 256; i2 += 64) Sc[wave][i2 >> 4][208 + (i2 & 15)] = 0;
  __syncthreads();

  const float scale = 1.f / 14.f;
  for (int st = wave; st < 13; st += 8) {
    int qb = st * 16;
    int s = qb + lr;
    bf16x8 aq0 = bz, aq1 = bz;
    if (s < 196) {
      aq0 = *reinterpret_cast<const bf16x8*>(q + base + (size_t)s * 64 + lg * 8);
      aq1 = *reinterpret_cast<const bf16x8*>(q + base + (size_t)s * 64 + 32 + lg * 8);
    }
    f32x4 sc[13];
#pragma unroll
    for (int t = 0; t < 13; t++) {
      bf16x8 bk0 = *reinterpret_cast<const bf16x8*>(&Kl[t * 16 + lr][lg * 8]);
      bf16x8 bk1 = *reinterpret_cast<const bf16x8*>(&Kl[t * 16 + lr][32 + lg * 8]);
      f32x4 z = {0.f, 0.f, 0.f, 0.f};
      z = mfma16(aq0, bk0, z);
      z = mfma16(aq1, bk1, z);
      sc[t] = z;
    }
    float mx[4] = {-1e30f, -1e30f, -1e30f, -1e30f};
#pragma unroll
    for (int t = 0; t < 13; t++) {
      int tc = t * 16 + lr;
#pragma unroll
      for (int r = 0; r < 4; r++) {
        float xv = (tc < 196) ? sc[t][r] * scale : -1e30f;
        sc[t][r] = xv;
        mx[r] = fmaxf(mx[r], xv);
      }
    }
#pragma unroll
    for (int r = 0; r < 4; r++)
#pragma unroll
      for (int mm = 1; mm < 16; mm <<= 1) mx[r] = fmaxf(mx[r], __shfl_xor(mx[r], mm, 64));
    float sm[4] = {0.f, 0.f, 0.f, 0.f};
#pragma unroll
    for (int t = 0; t < 13; t++)
#pragma unroll
      for (int r = 0; r < 4; r++) {
        float e = __expf(sc[t][r] - mx[r]);
        sc[t][r] = e;
        sm[r] += e;
      }
#pragma unroll
    for (int r = 0; r < 4; r++)
#pragma unroll
      for (int mm = 1; mm < 16; mm <<= 1) sm[r] += __shfl_xor(sm[r], mm, 64);
    float inv[4];
#pragma unroll
    for (int r = 0; r < 4; r++) inv[r] = 1.f / sm[r];
#pragma unroll
    for (int t = 0; t < 13; t++)
#pragma unroll
      for (int r = 0; r < 4; r++)
        Sc[wave][lg * 4 + r][t * 16 + lr] = f2bf(sc[t][r] * inv[r]);
    asm volatile("s_waitcnt lgkmcnt(0)" ::: "memory");
    bf16x8 ap[7];
#pragma unroll
    for (int ks = 0; ks < 7; ks++)
      ap[ks] = *reinterpret_cast<const bf16x8*>(&Sc[wave][lr][ks * 32 + lg * 8]);
#pragma unroll
    for (int nt = 0; nt < 4; nt++) {
      f32x4 o = {0.f, 0.f, 0.f, 0.f};
#pragma unroll
      for (int ks = 0; ks < 7; ks++) {
        bf16x8 bv = *reinterpret_cast<const bf16x8*>(&Vt[nt * 16 + lr][ks * 32 + lg * 8]);
        o = mfma16(ap[ks], bv, o);
      }
#pragma unroll
      for (int r = 0; r < 4; r++) {
        int s2 = qb + lg * 4 + r;
        if (s2 < 196) h[(size_t)(b * 196 + s2) * 768 + hh * 64 + nt * 16 + lr] += o[r];
      }
    }
  }
}

__global__ __launch_bounds__(256) void k_fc(const float* __restrict__ hm,
                                            const float* __restrict__ w,
                                            const float* __restrict__ bias,
                                            float* __restrict__ out) {
  int b = blockIdx.x, n = blockIdx.y * 256 + threadIdx.x;
  if (n >= 1000) return;
  float acc = bias[n];
  for (int d = 0; d < 768; d++) acc += hm[b * 768 + d] * w[d * 1000 + n];
  out[b * 1000 + n] = acc;
}

extern "C" void kernel_launch(void* const* d_in, const int* in_sizes, int n_in,
                              void* d_out, int out_size, void* d_ws, size_t ws_size,
                              hipStream_t stream) {
  const float* x      = (const float*)d_in[0];
  const float* conv_w = (const float*)d_in[1];
  const float* conv_b = (const float*)d_in[2];
  const float* pos    = (const float*)d_in[3];
  const float* ln1_s  = (const float*)d_in[4];
  const float* ln1_b  = (const float*)d_in[5];
  const float* wq     = (const float*)d_in[6];
  const float* wk     = (const float*)d_in[7];
  const float* wv     = (const float*)d_in[8];
  const float* ln2_s  = (const float*)d_in[9];
  const float* ln2_b  = (const float*)d_in[10];
  const float* w1     = (const float*)d_in[11];
  const float* b1     = (const float*)d_in[12];
  const float* w2     = (const float*)d_in[13];
  const float* b2     = (const float*)d_in[14];
  const float* fc_w   = (const float*)d_in[15];
  const float* fc_b   = (const float*)d_in[16];
  float* out = (float*)d_out;

  char* p = (char*)d_ws;
  auto alloc = [&](size_t bytes) {
    char* r = p;
    p += (bytes + 255) & ~(size_t)255;
    return r;
  };
  const size_t M = 6272, MP = 6400, QSZ = 4816896;
  float* h              = (float*)alloc(M * 768 * 4);
  unsigned short* xn    = (unsigned short*)alloc(MP * 768 * 2);
  unsigned short* qkv   = (unsigned short*)alloc(3 * QSZ * 2);
  unsigned short* y1    = (unsigned short*)alloc(MP * 3072 * 2);
  float* hm             = (float*)alloc(32 * 768 * 4);

  // weight buffers: hoist all 12 layers if workspace permits (deterministic:
  // ws_size is fixed by the harness).
  size_t used = (size_t)(p - (char*)d_ws);
  size_t perL = ((size_t)2304 * 768 + 2 * (size_t)3072 * 768) * 2;  // bytes/layer
  bool hoist = ws_size >= used + 12 * perL + 4096;
  int nw = hoist ? 12 : 1;
  unsigned short* wqkvT = (unsigned short*)alloc((size_t)nw * 2304 * 768 * 2);
  unsigned short* w1T   = (unsigned short*)alloc((size_t)nw * 3072 * 768 * 2);
  unsigned short* w2T   = (unsigned short*)alloc((size_t)nw * 3072 * 768 * 2);

  unsigned short* cwB   = qkv;          // alias: patch gemm done before qkv written
  float* part           = (float*)qkv;  // alias: qkv dead between attn and next QKV

  k_cvt<<<576, 256, 0, stream>>>(conv_w, cwB);
  k_im2col<<<4704, 256, 0, stream>>>(x, xn);
  k_gemm<0, 128><<<dim3(6, 49, 1), 256, 0, stream>>>(xn, cwB, 768, 24, conv_b, pos, h,
                                                     nullptr);
  if (hoist)
    k_wconvert_all<<<19008, 256, 0, stream>>>(wq, wk, wv, w1, w2, wqkvT, w1T, w2T);

  for (int l = 0; l < 12; l++) {
    unsigned short* wqkvT_l = wqkvT + (hoist ? (size_t)l * 1769472 : 0);
    unsigned short* w1T_l   = w1T + (hoist ? (size_t)l * 2359296 : 0);
    unsigned short* w2T_l   = w2T + (hoist ? (size_t)l * 2359296 : 0);
    if (!hoist)
      k_wconvert<<<1584, 256, 0, stream>>>(
          wq + (size_t)l * 589824, wk + (size_t)l * 589824, wv + (size_t)l * 589824,
          w1 + (size_t)l * 2359296, w2 + (size_t)l * 2359296, wqkvT_l, w1T_l, w2T_l);
    if (l == 0)
      k_ln<0><<<1568, 256, 0, stream>>>(h, nullptr, ln1_s, ln1_b, xn);
    else
      k_ln<1><<<1568, 256, 0, stream>>>(h, part, ln1_s + l * 768, ln1_b + l * 768, xn);
    k_gemm256p<1><<<dim3(9, 25), 512, 0, stream>>>(xn, wqkvT_l, nullptr, qkv);
    k_attn<<<384, 512, 0, stream>>>(qkv, qkv + QSZ, qkv + 2 * QSZ, h);
    k_ln<0><<<1568, 256, 0, stream>>>(h, nullptr, ln2_s + l * 768, ln2_b + l * 768, xn);
    k_gemm256p<2><<<dim3(12, 25), 512, 0, stream>>>(xn, w1T_l, b1 + (size_t)l * 3072, y1);
    k_gemm<3, 64><<<dim3(12, 49, 2), 256, 0, stream>>>(y1, w2T_l, 3072, 48,
                                                       b2 + (size_t)l * 768, nullptr, h,
                                                       part);
  }
  k_mean_r<<<dim3(32, 3), 256, 0, stream>>>(h, part, hm);
  k_fc<<<dim3(32, 4), 256, 0, stream>>>(hm, fc_w, fc_b, out);
}

// Round 16
// 2841.727 us; speedup vs baseline: 1.0034x; 1.0034x over previous
//
#include <hip/hip_runtime.h>
#include <hip/hip_bf16.h>

typedef __attribute__((ext_vector_type(8))) short bf16x8;
typedef __attribute__((ext_vector_type(4))) short bf16x4;
typedef __attribute__((ext_vector_type(4))) float f32x4;

#define DEVI static __device__ __forceinline__

DEVI unsigned short f2bf(float f) {
  __hip_bfloat16 h = __float2bfloat16(f);
  return __builtin_bit_cast(unsigned short, h);
}

DEVI f32x4 mfma16(bf16x8 a, bf16x8 b, f32x4 c) {
  return __builtin_amdgcn_mfma_f32_16x16x32_bf16(a, b, c, 0, 0, 0);
}

// async global->LDS, 16B per lane; LDS dest is wave-uniform base + lane*16
DEVI void gload16(const unsigned short* g, unsigned short* l) {
  __builtin_amdgcn_global_load_lds(
      (const __attribute__((address_space(1))) void*)g,
      (__attribute__((address_space(3))) void*)l, 16, 0, 0);
}

// fast erf (Abramowitz-Stegun 7.1.26, |err| <= 1.5e-7)
DEVI float erf_fast(float x) {
  float ax = fabsf(x);
  float t = 1.f / (1.f + 0.3275911f * ax);
  float poly = ((((1.061405429f * t - 1.453152027f) * t + 1.421413741f) * t -
                 0.284496736f) * t + 0.254829592f) * t;
  float e = __expf(-x * x);
  float er = 1.f - poly * e;
  return copysignf(er, x);
}

// ---------------- im2col: x[32,3,224,224] -> A[6272][768] bf16 -------------
__global__ __launch_bounds__(256) void k_im2col(const float* __restrict__ x,
                                                unsigned short* __restrict__ A) {
  int t = blockIdx.x * 256 + threadIdx.x;
  int m = t / 192;
  int qq = t - m * 192;
  int kk = qq * 4;
  int c = kk >> 8;
  int r = kk & 255;
  int i = r >> 4;
  int j = r & 15;
  int b = m / 196;
  int s = m - b * 196;
  int ph = s / 14;
  int pw = s - ph * 14;
  const float* src = x + ((size_t)((b * 3 + c) * 224 + ph * 16 + i)) * 224 + pw * 16 + j;
  f32x4 v = *reinterpret_cast<const f32x4*>(src);
  bf16x4 o;
  o[0] = (short)f2bf(v[0]); o[1] = (short)f2bf(v[1]);
  o[2] = (short)f2bf(v[2]); o[3] = (short)f2bf(v[3]);
  *reinterpret_cast<bf16x4*>(A + (size_t)m * 768 + kk) = o;
}

// ---------------- elementwise f32 -> bf16 (conv_w is already [N][K]) -------
__global__ __launch_bounds__(256) void k_cvt(const float* __restrict__ in,
                                             unsigned short* __restrict__ out) {
  int t = blockIdx.x * 256 + threadIdx.x;
  f32x4 v = *reinterpret_cast<const f32x4*>(in + (size_t)t * 4);
  bf16x4 o;
  o[0] = (short)f2bf(v[0]); o[1] = (short)f2bf(v[1]);
  o[2] = (short)f2bf(v[2]); o[3] = (short)f2bf(v[3]);
  *reinterpret_cast<bf16x4*>(out + (size_t)t * 4) = o;
}

// ---------------- transpose-convert: W[K][N] f32 -> Wt[N][K] bf16 ----------
// Write phase stores TRANSPOSED into LDS (scalar b16 writes, stride-66 row
// keeps them ~4-way); read phase is then a vector ds_read_b128 + 16B global
// store (full 128B segments per output row).
DEVI void transpose_tile(const float* __restrict__ in, unsigned short* __restrict__ out,
                         int K, int N, int kt, int nt, unsigned short (*tile)[66]) {
  int r = threadIdx.x >> 4;
  int c4 = (threadIdx.x & 15) * 4;
  int k0 = kt * 64, n0 = nt * 64;
#pragma unroll
  for (int rr0 = 0; rr0 < 4; rr0++) {
    int rr = r + rr0 * 16;  // source k-row
    f32x4 v = *reinterpret_cast<const f32x4*>(in + (size_t)(k0 + rr) * N + n0 + c4);
#pragma unroll
    for (int j = 0; j < 4; j++) tile[c4 + j][rr] = f2bf(v[j]);  // tileT[n][k]
  }
  __syncthreads();
#pragma unroll
  for (int it = 0; it < 2; it++) {
    int t = it * 256 + threadIdx.x;
    int rr = t >> 3;          // output n-row
    int c8 = (t & 7) * 8;     // k-group
    bf16x8 o = *reinterpret_cast<const bf16x8*>(&tile[rr][c8]);
    *reinterpret_cast<bf16x8*>(out + (size_t)(n0 + rr) * K + k0 + c8) = o;
  }
}

DEVI void wconvert_body(const float* wq, const float* wk, const float* wv,
                        const float* w1, const float* w2,
                        unsigned short* wqkvT, unsigned short* w1T,
                        unsigned short* w2T, int bid,
                        unsigned short (*tile)[66]) {
  if (bid < 432) {
    int mm = bid / 144, t2 = bid - mm * 144;
    const float* in = (mm == 0) ? wq : ((mm == 1) ? wk : wv);
    transpose_tile(in, wqkvT + (size_t)mm * 768 * 768, 768, 768, t2 / 12, t2 % 12, tile);
  } else if (bid < 1008) {
    int t2 = bid - 432;
    transpose_tile(w1, w1T, 768, 3072, t2 / 48, t2 % 48, tile);
  } else {
    int t2 = bid - 1008;
    transpose_tile(w2, w2T, 3072, 768, t2 / 12, t2 % 12, tile);
  }
}

__global__ __launch_bounds__(256) void k_wconvert(
    const float* __restrict__ wq, const float* __restrict__ wk, const float* __restrict__ wv,
    const float* __restrict__ w1, const float* __restrict__ w2,
    unsigned short* __restrict__ wqkvT, unsigned short* __restrict__ w1T,
    unsigned short* __restrict__ w2T) {
  __shared__ unsigned short tile[64][66];
  wconvert_body(wq, wk, wv, w1, w2, wqkvT, w1T, w2T, blockIdx.x, tile);
}

// all-12-layer variant (one launch; used when workspace permits)
__global__ __launch_bounds__(256) void k_wconvert_all(
    const float* __restrict__ wq, const float* __restrict__ wk, const float* __restrict__ wv,
    const float* __restrict__ w1, const float* __restrict__ w2,
    unsigned short* __restrict__ wqkvT, unsigned short* __restrict__ w1T,
    unsigned short* __restrict__ w2T) {
  __shared__ unsigned short tile[64][66];
  int l = blockIdx.x / 1584, bid = blockIdx.x - l * 1584;
  wconvert_body(wq + (size_t)l * 589824, wk + (size_t)l * 589824, wv + (size_t)l * 589824,
                w1 + (size_t)l * 2359296, w2 + (size_t)l * 2359296,
                wqkvT + (size_t)l * 1769472, w1T + (size_t)l * 2359296,
                w2T + (size_t)l * 2359296, bid, tile);
}

// -------- LayerNorm (optionally fused with split-K combine) ----------------
// RED=0: xn = LN(h)
// RED=1: v = h + part; h = v; xn = LN(v)
template <int RED>
__global__ __launch_bounds__(256) void k_ln(float* __restrict__ h,
                                            const float* __restrict__ part,
                                            const float* __restrict__ sc,
                                            const float* __restrict__ bi,
                                            unsigned short* __restrict__ xn) {
  int wave = threadIdx.x >> 6, lane = threadIdx.x & 63;
  int row = blockIdx.x * 4 + wave;
  float* hr = h + (size_t)row * 768;
  const float* pr = part + (size_t)row * 768;
  f32x4 v[3];
  float sum = 0.f;
#pragma unroll
  for (int i = 0; i < 3; i++) {
    v[i] = *reinterpret_cast<const f32x4*>(hr + i * 256 + lane * 4);
    if (RED) {
      f32x4 pv = *reinterpret_cast<const f32x4*>(pr + i * 256 + lane * 4);
#pragma unroll
      for (int c = 0; c < 4; c++) v[i][c] += pv[c];
      *reinterpret_cast<f32x4*>(hr + i * 256 + lane * 4) = v[i];
    }
    sum += v[i][0] + v[i][1] + v[i][2] + v[i][3];
  }
#pragma unroll
  for (int m = 1; m < 64; m <<= 1) sum += __shfl_xor(sum, m, 64);
  float mean = sum * (1.f / 768.f);
  float var = 0.f;
#pragma unroll
  for (int i = 0; i < 3; i++)
#pragma unroll
    for (int c = 0; c < 4; c++) { float d = v[i][c] - mean; var += d * d; }
#pragma unroll
  for (int m = 1; m < 64; m <<= 1) var += __shfl_xor(var, m, 64);
  float rs = rsqrtf(var * (1.f / 768.f) + 1e-5f);
#pragma unroll
  for (int i = 0; i < 3; i++) {
    int col = i * 256 + lane * 4;
    f32x4 s4 = *reinterpret_cast<const f32x4*>(sc + col);
    f32x4 b4 = *reinterpret_cast<const f32x4*>(bi + col);
    bf16x4 o;
#pragma unroll
    for (int c = 0; c < 4; c++) o[c] = (short)f2bf((v[i][c] - mean) * rs * s4[c] + b4[c]);
    *reinterpret_cast<bf16x4*>(xn + (size_t)row * 768 + col) = o;
  }
}

// ---------------- 128xBN-tile GEMM (R4-proven structure), split-K ----------
// EPI 0 (BN=128): patch -> h = acc + conv_b[n] + pos[s][n]      (z=1)
// EPI 3 (BN=64):  mlp2  -> split0: h += acc + b2[n]; split1: pOut = acc (z=2)
template <int EPI, int BN>
__global__ __launch_bounds__(256) void k_gemm(
    const unsigned short* __restrict__ A, const unsigned short* __restrict__ Bt, int K,
    int nks, const float* __restrict__ bias, const float* __restrict__ aux,
    float* __restrict__ outF, float* __restrict__ pOut) {
  constexpr int NI = BN / 32;  // B frags per wave
  constexpr int BR = BN / 64;  // B staging rounds
  __shared__ __align__(16) unsigned short As[2][128 * 32];
  __shared__ __align__(16) unsigned short Bs[2][BN * 32];

  int GX = gridDim.x, GY = gridDim.y, GZ = gridDim.z;
  int nb = GX * GY * GZ;
  int lin = (blockIdx.z * GY + blockIdx.y) * GX + blockIdx.x;
  int q = nb >> 3, r8 = nb & 7;
  int xcd = lin & 7, off = lin >> 3;
  int wid = (xcd < r8 ? xcd * (q + 1) : r8 * (q + 1) + (xcd - r8) * q) + off;
  int t2 = GX * GY;
  int sz = wid / t2;
  int w2 = wid - sz * t2;
  const int GM = 8;
  int per = GM * GX;
  int g = w2 / per;
  int first_m = g * GM;
  int gm = min(GM, GY - first_m);
  int rem = w2 - g * per;
  int mt = first_m + rem % gm;
  int nt = rem / gm;
  int m0 = mt * 128, n0 = nt * BN;
  int kb = sz * nks * 32;

  int tid = threadIdx.x;
  int wave = tid >> 6, lane = tid & 63;
  int wm = (wave >> 1) * 64, wn = (wave & 1) * (NI * 16);
  int lr = lane & 15, lg = lane >> 4;

  f32x4 acc[4][NI];
  const f32x4 fz = {0.f, 0.f, 0.f, 0.f};
#pragma unroll
  for (int i = 0; i < 4; i++)
#pragma unroll
    for (int j = 0; j < NI; j++) acc[i][j] = fz;

  int srow = wave * 16 + (lane >> 2);
  int scol = (lane & 3) * 8;
  const unsigned short* Ag = A + (size_t)(m0 + srow) * K + scol + kb;
  const unsigned short* Bg = Bt + (size_t)(n0 + srow) * K + scol + kb;
  int lofs = wave * 16 * 32;

#pragma unroll
  for (int j = 0; j < 2; j++)
    gload16(Ag + (size_t)j * 64 * K, &As[0][lofs + j * 64 * 32]);
#pragma unroll
  for (int j = 0; j < BR; j++)
    gload16(Bg + (size_t)j * 64 * K, &Bs[0][lofs + j * 64 * 32]);
  __syncthreads();

  for (int kt = 0; kt < nks - 1; kt++) {
    int cur = kt & 1;
    int k0 = (kt + 1) << 5;
#pragma unroll
    for (int j = 0; j < 2; j++)
      gload16(Ag + (size_t)j * 64 * K + k0, &As[cur ^ 1][lofs + j * 64 * 32]);
#pragma unroll
    for (int j = 0; j < BR; j++)
      gload16(Bg + (size_t)j * 64 * K + k0, &Bs[cur ^ 1][lofs + j * 64 * 32]);
    bf16x8 a[4], b[NI];
#pragma unroll
    for (int i = 0; i < 4; i++)
      a[i] = *reinterpret_cast<const bf16x8*>(&As[cur][(wm + i * 16 + lr) * 32 + lg * 8]);
#pragma unroll
    for (int i = 0; i < NI; i++)
      b[i] = *reinterpret_cast<const bf16x8*>(&Bs[cur][(wn + i * 16 + lr) * 32 + lg * 8]);
#pragma unroll
    for (int mi = 0; mi < 4; mi++)
#pragma unroll
      for (int ni = 0; ni < NI; ni++) acc[mi][ni] = mfma16(a[mi], b[ni], acc[mi][ni]);
    __syncthreads();
  }
  {
    int cur = (nks - 1) & 1;
    bf16x8 a[4], b[NI];
#pragma unroll
    for (int i = 0; i < 4; i++)
      a[i] = *reinterpret_cast<const bf16x8*>(&As[cur][(wm + i * 16 + lr) * 32 + lg * 8]);
#pragma unroll
    for (int i = 0; i < NI; i++)
      b[i] = *reinterpret_cast<const bf16x8*>(&Bs[cur][(wn + i * 16 + lr) * 32 + lg * 8]);
#pragma unroll
    for (int mi = 0; mi < 4; mi++)
#pragma unroll
      for (int ni = 0; ni < NI; ni++) acc[mi][ni] = mfma16(a[mi], b[ni], acc[mi][ni]);
  }

#pragma unroll
  for (int mi = 0; mi < 4; mi++) {
    int mb = m0 + wm + mi * 16 + lg * 4;
    int bb = mb / 196;
    int s0 = mb - bb * 196;
#pragma unroll
    for (int ni = 0; ni < NI; ni++) {
      int n = n0 + wn + ni * 16 + lr;
      int s = s0;
#pragma unroll
      for (int r = 0; r < 4; r++) {
        int m = mb + r;
        float val = acc[mi][ni][r];
        if (EPI == 0) {
          outF[(size_t)m * 768 + n] = val + bias[n] + aux[(size_t)s * 768 + n];
          s++;
          if (s == 196) s = 0;
        } else {
          if (sz == 0) outF[(size_t)m * 768 + n] += val + bias[n];
          else pOut[(size_t)m * 768 + n] = val;
        }
      }
    }
  }
}

// ---------------- mean over tokens (+ split-K combine) ---------------------
__global__ __launch_bounds__(256) void k_mean_r(const float* __restrict__ h,
                                                const float* __restrict__ part,
                                                float* __restrict__ hm) {
  int b = blockIdx.x, d = blockIdx.y * 256 + threadIdx.x;
  float acc = 0.f;
  for (int s = 0; s < 196; s++) {
    size_t i = (size_t)(b * 196 + s) * 768 + d;
    acc += h[i] + part[i];
  }
  hm[b * 768 + d] = acc * (1.f / 196.f);
}

// ---------------- 256-tile 8-wave GEMM, quad-buffer + 2-phase/K-tile -------
// (R10/R13-proven; unchanged)  EPI 1: qkv scatter bf16; EPI 2: gelu->bf16.
template <int EPI>
__global__ __launch_bounds__(512, 2) void k_gemm256p(
    const unsigned short* __restrict__ A, const unsigned short* __restrict__ Bt,
    const float* __restrict__ bias, unsigned short* __restrict__ outB) {
  const int K = 768, NK = 24;
  __shared__ __align__(16) unsigned short LDS[4][16384];
  const int MVALID = 6272;

  int GX = gridDim.x, GY = gridDim.y;
  int nb = GX * GY;
  int lin = blockIdx.y * GX + blockIdx.x;
  int q = nb >> 3, r8 = nb & 7;
  int xcd = lin & 7, off = lin >> 3;
  int wid = (xcd < r8 ? xcd * (q + 1) : r8 * (q + 1) + (xcd - r8) * q) + off;
  const int GM = 4;
  int per = GM * GX;
  int g = wid / per;
  int first_m = g * GM;
  int gm = min(GM, GY - first_m);
  int rem = wid - g * per;
  int mt = first_m + rem % gm;
  int nt = rem / gm;
  int m0 = mt * 256, n0 = nt * 256;

  int tid = threadIdx.x;
  int w = tid >> 6, lane = tid & 63;
  int wm = w >> 2, wn = w & 3;
  int lr = lane & 15, lg = lane >> 4;

  f32x4 acc[8][4];
  const f32x4 fz = {0.f, 0.f, 0.f, 0.f};
#pragma unroll
  for (int i = 0; i < 8; i++)
#pragma unroll
    for (int j = 0; j < 4; j++) acc[i][j] = fz;

  int srow = w * 16 + (lane >> 2);
  int scol = ((lane & 3) ^ ((lane >> 3) & 3)) * 8;
  const unsigned short* Ag = A + (size_t)(m0 + srow) * K + scol;
  const unsigned short* Bg = Bt + (size_t)(n0 + srow) * K + scol;
  int ldst = w * 512;

  int colsw = (lg ^ ((lr >> 1) & 3)) * 8;
  int rofA = wm * 4096 + lr * 32 + colsw;
  int rofB = 8192 + wn * 2048 + lr * 32 + colsw;

#define STAGEA(kt)                                                          \
  {                                                                         \
    unsigned short* d_ = &LDS[(kt) & 3][0];                                 \
    const unsigned short* a_ = Ag + (kt) * 32;                              \
    gload16(a_, d_ + ldst);                                                 \
    gload16(a_ + (size_t)128 * K, d_ + 4096 + ldst);                        \
  }
#define STAGEB(kt)                                                          \
  {                                                                         \
    unsigned short* d_ = &LDS[(kt) & 3][0];                                 \
    const unsigned short* b_ = Bg + (kt) * 32;                              \
    gload16(b_, d_ + 8192 + ldst);                                          \
    gload16(b_ + (size_t)128 * K, d_ + 12288 + ldst);                       \
  }

#define KTILE(ktv, VMSTR, STG, LAST)                                         \
  {                                                                          \
    const int kt_ = (ktv);                                                   \
    const unsigned short* buf_ = &LDS[kt_ & 3][0];                           \
    bf16x8 afr[8], bfr[2];                                                   \
    _Pragma("unroll") for (int mi = 0; mi < 8; mi++) afr[mi] =               \
        *reinterpret_cast<const bf16x8*>(buf_ + rofA + mi * 512);            \
    _Pragma("unroll") for (int ni = 0; ni < 2; ni++) bfr[ni] =               \
        *reinterpret_cast<const bf16x8*>(buf_ + rofB + ni * 512);            \
    if (STG) STAGEA(kt_ + 3);                                                \
    asm volatile("s_waitcnt lgkmcnt(0)" ::: "memory");                       \
    __builtin_amdgcn_sched_barrier(0);                                       \
    __builtin_amdgcn_s_setprio(1);                                           \
    _Pragma("unroll") for (int mi = 0; mi < 8; mi++)                         \
        _Pragma("unroll") for (int ni = 0; ni < 2; ni++)                     \
            acc[mi][ni] = mfma16(afr[mi], bfr[ni], acc[mi][ni]);             \
    __builtin_amdgcn_s_setprio(0);                                           \
    __builtin_amdgcn_s_barrier();                                            \
    _Pragma("unroll") for (int ni = 0; ni < 2; ni++) bfr[ni] =               \
        *reinterpret_cast<const bf16x8*>(buf_ + rofB + (2 + ni) * 512);      \
    if (STG) STAGEB(kt_ + 3);                                                \
    asm volatile("s_waitcnt lgkmcnt(0)" ::: "memory");                       \
    __builtin_amdgcn_sched_barrier(0);                                       \
    __builtin_amdgcn_s_setprio(1);                                           \
    _Pragma("unroll") for (int mi = 0; mi < 8; mi++)                         \
        _Pragma("unroll") for (int ni = 0; ni < 2; ni++)                     \
            acc[mi][2 + ni] = mfma16(afr[mi], bfr[ni], acc[mi][2 + ni]);     \
    __builtin_amdgcn_s_setprio(0);                                           \
    if (!LAST) {                                                             \
      asm volatile("s_waitcnt vmcnt(" VMSTR ")" ::: "memory");               \
      __builtin_amdgcn_s_barrier();                                          \
    }                                                                        \
  }

  STAGEA(0); STAGEB(0);
  STAGEA(1); STAGEB(1);
  STAGEA(2); STAGEB(2);
  asm volatile("s_waitcnt vmcnt(8)" ::: "memory");
  __builtin_amdgcn_s_barrier();

  for (int kt = 0; kt < NK - 3; kt++) KTILE(kt, "8", true, false);
  KTILE(NK - 3, "4", false, false);
  KTILE(NK - 2, "0", false, false);
  KTILE(NK - 1, "0", false, true);
#undef KTILE
#undef STAGEA
#undef STAGEB

  if (EPI == 1) {
#pragma unroll
    for (int ni = 0; ni < 4; ni++) {
      int n = n0 + wn * 64 + ni * 16 + lr;
      int which = (n >= 1536) ? 2 : ((n >= 768) ? 1 : 0);
      int n7 = n - which * 768;
      int hd = n7 >> 6, dh = n7 & 63;
      unsigned short* ob = outB + (size_t)which * 4816896 + dh;
#pragma unroll
      for (int mi = 0; mi < 8; mi++) {
        int mb = m0 + wm * 128 + mi * 16 + lg * 4;
        if (mb >= MVALID) continue;
        int bb = mb / 196;
        int s = mb - bb * 196;
#pragma unroll
        for (int r = 0; r < 4; r++) {
          ob[((size_t)((bb * 12 + hd) * 196 + s) << 6)] = f2bf(acc[mi][ni][r]);
          s++;
          if (s == 196) { s = 0; bb++; }
        }
      }
    }
  } else {
#pragma unroll
    for (int mi = 0; mi < 8; mi++) {
      int mb = m0 + wm * 128 + mi * 16 + lg * 4;
      if (mb >= MVALID) continue;
#pragma unroll
      for (int ni = 0; ni < 4; ni++) {
        int n = n0 + wn * 64 + ni * 16 + lr;
#pragma unroll
        for (int r = 0; r < 4; r++) {
          int m = mb + r;
          float u = acc[mi][ni][r] + bias[n];
          float gg = 0.5f * u * (1.f + erf_fast(u * 0.70710678118654752f));
          outB[(size_t)m * 3072 + n] = f2bf(gg);
        }
      }
    }
  }
}

// ---------------- attention: 512 threads (8 waves), 2 strips/wave ----------
__global__ __launch_bounds__(512) void k_attn(const unsigned short* __restrict__ q,
                                              const unsigned short* __restrict__ k,
                                              const unsigned short* __restrict__ v,
                                              float* __restrict__ h) {
  __shared__ __align__(16) unsigned short Kl[208][72];
  __shared__ __align__(16) unsigned short Vt[64][248];
  __shared__ __align__(16) unsigned short Sc[8][16][232];
  int bh = blockIdx.x;
  int b = bh / 12, hh = bh - b * 12;
  size_t base = (size_t)bh * 196 * 64;
  int tid = threadIdx.x, wave = tid >> 6, lane = tid & 63;
  int lr = lane & 15, lg = lane >> 4;

  const bf16x8 bz = {0, 0, 0, 0, 0, 0, 0, 0};
  for (int u = tid; u < 208 * 8; u += 512) {
    int row = u >> 3, c8 = (u & 7) * 8;
    bf16x8 val = bz;
    if (row < 196) val = *reinterpret_cast<const bf16x8*>(k + base + row * 64 + c8);
    *reinterpret_cast<bf16x8*>(&Kl[row][c8]) = val;
  }
  for (int u = tid; u < 224 * 8; u += 512) {
    int t = u >> 3, d8 = (u & 7) * 8;
    bf16x8 val = bz;
    if (t < 196) val = *reinterpret_cast<const bf16x8*>(v + base + t * 64 + d8);
#pragma unroll
    for (int i = 0; i < 8; i++) Vt[d8 + i][t] = (unsigned short)val[i];
  }
  for (int i2 = lane; i2 < 256; i2 += 64) Sc[wave][i2 >> 4][208 + (i2 & 15)] = 0;
  __syncthreads();

  const float scale = 1.f / 14.f;
  for (int st = wave; st < 13; st += 8) {
    int qb = st * 16;
    int s = qb + lr;
    bf16x8 aq0 = bz, aq1 = bz;
    if (s < 196) {
      aq0 = *reinterpret_cast<const bf16x8*>(q + base + (size_t)s * 64 + lg * 8);
      aq1 = *reinterpret_cast<const bf16x8*>(q + base + (size_t)s * 64 + 32 + lg * 8);
    }
    f32x4 sc[13];
#pragma unroll
    for (int t = 0; t < 13; t++) {
      bf16x8 bk0 = *reinterpret_cast<const bf16x8*>(&Kl[t * 16 + lr][lg * 8]);
      bf16x8 bk1 = *reinterpret_cast<const bf16x8*>(&Kl[t * 16 + lr][32 + lg * 8]);
      f32x4 z = {0.f, 0.f, 0.f, 0.f};
      z = mfma16(aq0, bk0, z);
      z = mfma16(aq1, bk1, z);
      sc[t] = z;
    }
    float mx[4] = {-1e30f, -1e30f, -1e30f, -1e30f};
#pragma unroll
    for (int t = 0; t < 13; t++) {
      int tc = t * 16 + lr;
#pragma unroll
      for (int r = 0; r < 4; r++) {
        float xv = (tc < 196) ? sc[t][r] * scale : -1e30f;
        sc[t][r] = xv;
        mx[r] = fmaxf(mx[r], xv);
      }
    }
#pragma unroll
    for (int r = 0; r < 4; r++)
#pragma unroll
      for (int mm = 1; mm < 16; mm <<= 1) mx[r] = fmaxf(mx[r], __shfl_xor(mx[r], mm, 64));
    float sm[4] = {0.f, 0.f, 0.f, 0.f};
#pragma unroll
    for (int t = 0; t < 13; t++)
#pragma unroll
      for (int r = 0; r < 4; r++) {
        float e = __expf(sc[t][r] - mx[r]);
        sc[t][r] = e;
        sm[r] += e;
      }
#pragma unroll
    for (int r = 0; r < 4; r++)
#pragma unroll
      for (int mm = 1; mm < 16; mm <<= 1) sm[r] += __shfl_xor(sm[r], mm, 64);
    float inv[4];
#pragma unroll
    for (int r = 0; r < 4; r++) inv[r] = 1.f / sm[r];
#pragma unroll
    for (int t = 0; t < 13; t++)
#pragma unroll
      for (int r = 0; r < 4; r++)
        Sc[wave][lg * 4 + r][t * 16 + lr] = f2bf(sc[t][r] * inv[r]);
    asm volatile("s_waitcnt lgkmcnt(0)" ::: "memory");
    bf16x8 ap[7];
#pragma unroll
    for (int ks = 0; ks < 7; ks++)
      ap[ks] = *reinterpret_cast<const bf16x8*>(&Sc[wave][lr][ks * 32 + lg * 8]);
#pragma unroll
    for (int nt = 0; nt < 4; nt++) {
      f32x4 o = {0.f, 0.f, 0.f, 0.f};
#pragma unroll
      for (int ks = 0; ks < 7; ks++) {
        bf16x8 bv = *reinterpret_cast<const bf16x8*>(&Vt[nt * 16 + lr][ks * 32 + lg * 8]);
        o = mfma16(ap[ks], bv, o);
      }
#pragma unroll
      for (int r = 0; r < 4; r++) {
        int s2 = qb + lg * 4 + r;
        if (s2 < 196) h[(size_t)(b * 196 + s2) * 768 + hh * 64 + nt * 16 + lr] += o[r];
      }
    }
  }
}

__global__ __launch_bounds__(256) void k_fc(const float* __restrict__ hm,
                                            const float* __restrict__ w,
                                            const float* __restrict__ bias,
                                            float* __restrict__ out) {
  int b = blockIdx.x, n = blockIdx.y * 256 + threadIdx.x;
  if (n >= 1000) return;
  float acc = bias[n];
  for (int d = 0; d < 768; d++) acc += hm[b * 768 + d] * w[d * 1000 + n];
  out[b * 1000 + n] = acc;
}

extern "C" void kernel_launch(void* const* d_in, const int* in_sizes, int n_in,
                              void* d_out, int out_size, void* d_ws, size_t ws_size,
                              hipStream_t stream) {
  const float* x      = (const float*)d_in[0];
  const float* conv_w = (const float*)d_in[1];
  const float* conv_b = (const float*)d_in[2];
  const float* pos    = (const float*)d_in[3];
  const float* ln1_s  = (const float*)d_in[4];
  const float* ln1_b  = (const float*)d_in[5];
  const float* wq     = (const float*)d_in[6];
  const float* wk     = (const float*)d_in[7];
  const float* wv     = (const float*)d_in[8];
  const float* ln2_s  = (const float*)d_in[9];
  const float* ln2_b  = (const float*)d_in[10];
  const float* w1     = (const float*)d_in[11];
  const float* b1     = (const float*)d_in[12];
  const float* w2     = (const float*)d_in[13];
  const float* b2     = (const float*)d_in[14];
  const float* fc_w   = (const float*)d_in[15];
  const float* fc_b   = (const float*)d_in[16];
  float* out = (float*)d_out;

  char* p = (char*)d_ws;
  auto alloc = [&](size_t bytes) {
    char* r = p;
    p += (bytes + 255) & ~(size_t)255;
    return r;
  };
  const size_t M = 6272, MP = 6400, QSZ = 4816896;
  float* h              = (float*)alloc(M * 768 * 4);
  unsigned short* xn    = (unsigned short*)alloc(MP * 768 * 2);
  unsigned short* qkv   = (unsigned short*)alloc(3 * QSZ * 2);
  unsigned short* y1    = (unsigned short*)alloc(MP * 3072 * 2);
  float* hm             = (float*)alloc(32 * 768 * 4);

  // weight buffers: hoist all 12 layers if workspace permits (deterministic:
  // ws_size is fixed by the harness).
  size_t used = (size_t)(p - (char*)d_ws);
  size_t perL = ((size_t)2304 * 768 + 2 * (size_t)3072 * 768) * 2;  // bytes/layer
  bool hoist = ws_size >= used + 12 * perL + 4096;
  int nw = hoist ? 12 : 1;
  unsigned short* wqkvT = (unsigned short*)alloc((size_t)nw * 2304 * 768 * 2);
  unsigned short* w1T   = (unsigned short*)alloc((size_t)nw * 3072 * 768 * 2);
  unsigned short* w2T   = (unsigned short*)alloc((size_t)nw * 3072 * 768 * 2);

  unsigned short* cwB   = qkv;          // alias: patch gemm done before qkv written
  float* part           = (float*)qkv;  // alias: qkv dead between attn and next QKV

  k_cvt<<<576, 256, 0, stream>>>(conv_w, cwB);
  k_im2col<<<4704, 256, 0, stream>>>(x, xn);
  k_gemm<0, 128><<<dim3(6, 49, 1), 256, 0, stream>>>(xn, cwB, 768, 24, conv_b, pos, h,
                                                     nullptr);
  if (hoist)
    k_wconvert_all<<<19008, 256, 0, stream>>>(wq, wk, wv, w1, w2, wqkvT, w1T, w2T);

  for (int l = 0; l < 12; l++) {
    unsigned short* wqkvT_l = wqkvT + (hoist ? (size_t)l * 1769472 : 0);
    unsigned short* w1T_l   = w1T + (hoist ? (size_t)l * 2359296 : 0);
    unsigned short* w2T_l   = w2T + (hoist ? (size_t)l * 2359296 : 0);
    if (!hoist)
      k_wconvert<<<1584, 256, 0, stream>>>(
          wq + (size_t)l * 589824, wk + (size_t)l * 589824, wv + (size_t)l * 589824,
          w1 + (size_t)l * 2359296, w2 + (size_t)l * 2359296, wqkvT_l, w1T_l, w2T_l);
    if (l == 0)
      k_ln<0><<<1568, 256, 0, stream>>>(h, nullptr, ln1_s, ln1_b, xn);
    else
      k_ln<1><<<1568, 256, 0, stream>>>(h, part, ln1_s + l * 768, ln1_b + l * 768, xn);
    k_gemm256p<1><<<dim3(9, 25), 512, 0, stream>>>(xn, wqkvT_l, nullptr, qkv);
    k_attn<<<384, 512, 0, stream>>>(qkv, qkv + QSZ, qkv + 2 * QSZ, h);
    k_ln<0><<<1568, 256, 0, stream>>>(h, nullptr, ln2_s + l * 768, ln2_b + l * 768, xn);
    k_gemm256p<2><<<dim3(12, 25), 512, 0, stream>>>(xn, w1T_l, b1 + (size_t)l * 3072, y1);
    k_gemm<3, 64><<<dim3(12, 49, 2), 256, 0, stream>>>(y1, w2T_l, 3072, 48,
                                                       b2 + (size_t)l * 768, nullptr, h,
                                                       part);
  }
  k_mean_r<<<dim3(32, 3), 256, 0, stream>>>(h, part, hm);
  k_fc<<<dim3(32, 4), 256, 0, stream>>>(hm, fc_w, fc_b, out);
}